// Round 1
// baseline (409.185 us; speedup 1.0000x reference)
//
#include <hip/hip_runtime.h>

#define TOKENS 8192
#define IN_F   4096
#define OUT_F  4096

#define BM 128
#define BN 128
#define BK 64

typedef __attribute__((ext_vector_type(4))) float  f32x4;
typedef __attribute__((ext_vector_type(4))) int    i32x4;
typedef __attribute__((ext_vector_type(8))) unsigned short u16x8;
typedef __attribute__((ext_vector_type(8))) __bf16 bf16x8;

typedef const __attribute__((address_space(1))) void gas_void;
typedef __attribute__((address_space(3))) void las_void;

__device__ __forceinline__ unsigned short f2bf(float f) {
    unsigned int u = __builtin_bit_cast(unsigned int, f);
    u += 0x7fffu + ((u >> 16) & 1u);   // round-to-nearest-even
    return (unsigned short)(u >> 16);
}

// x fp32 -> bf16, 8 elements/thread
__global__ __launch_bounds__(256) void cvt_x_kernel(const float* __restrict__ x,
                                                    unsigned short* __restrict__ xb) {
    const int t = blockIdx.x * 256 + threadIdx.x;
    const f32x4* p = (const f32x4*)x + (size_t)t * 2;
    f32x4 a = p[0], b = p[1];
    u16x8 o;
#pragma unroll
    for (int j = 0; j < 4; ++j) { o[j] = f2bf(a[j]); o[4 + j] = f2bf(b[j]); }
    ((u16x8*)xb)[t] = o;
}

// ternary int32 * group scale -> bf16 W[OUT_F][IN_F], 8 elements/thread
// group index of flat element f is f/128; thread handles flat [t*8, t*8+8) -> group t/16
__global__ __launch_bounds__(256) void deq_w_kernel(const int* __restrict__ tern,
                                                    const float* __restrict__ scales,
                                                    unsigned short* __restrict__ wb) {
    const int t = blockIdx.x * 256 + threadIdx.x;
    const float s = scales[t >> 4];
    const i32x4* p = (const i32x4*)tern + (size_t)t * 2;
    i32x4 a = p[0], b = p[1];
    u16x8 o;
#pragma unroll
    for (int j = 0; j < 4; ++j) {
        o[j]     = f2bf((float)a[j] * s);
        o[4 + j] = f2bf((float)b[j] * s);
    }
    ((u16x8*)wb)[t] = o;
}

// C[M][N] = A[M][K] * B[N][K]^T   (bf16 in, fp32 out)
// 128x128 tile, BK=64, 4 waves (2x2), each wave owns a 64x64 subtile of C.
__global__ __launch_bounds__(256) void gemm_bt_kernel(const unsigned short* __restrict__ A,
                                                      const unsigned short* __restrict__ B,
                                                      float* __restrict__ C) {
    __shared__ __align__(16) unsigned short As[BM * BK];
    __shared__ __align__(16) unsigned short Bs[BN * BK];

    const int bn   = blockIdx.x;       // N block (0..31)
    const int bm   = blockIdx.y;       // M block (0..63)
    const int tid  = threadIdx.x;
    const int wave = tid >> 6;         // 0..3
    const int lane = tid & 63;
    const int wm   = wave >> 1;        // 0..1
    const int wn   = wave & 1;         // 0..1
    const int lg   = lane >> 4;        // 0..3  (k-chunk selector)
    const int lr   = lane & 15;        // row/col within fragment

    f32x4 acc[4][4] = {};

    const size_t a_base = (size_t)bm * BM * IN_F;
    const size_t b_base = (size_t)bn * BN * IN_F;

    for (int k0 = 0; k0 < IN_F; k0 += BK) {
        // --- stage A,B tiles: 16 chunks of 1KB each; chunk c covers rows 8c..8c+7
#pragma unroll
        for (int it = 0; it < 4; ++it) {
            const int chunk = it * 4 + wave;             // 0..15, wave-uniform
            const int e   = (chunk << 9) + lane * 8;     // element index in 128x64 tile
            const int row = e >> 6;
            const int col = e & 63;
            const unsigned short* ga = A + a_base + (size_t)row * IN_F + k0 + col;
            const unsigned short* gb = B + b_base + (size_t)row * IN_F + k0 + col;
            __builtin_amdgcn_global_load_lds((gas_void*)ga, (las_void*)(As + (chunk << 9)), 16, 0, 0);
            __builtin_amdgcn_global_load_lds((gas_void*)gb, (las_void*)(Bs + (chunk << 9)), 16, 0, 0);
        }
        __syncthreads();   // compiler emits vmcnt(0) drain before barrier

        // --- compute: 2 k-subtiles of 32, 4x4 fragments of 16x16 per wave
#pragma unroll
        for (int kk = 0; kk < 2; ++kk) {
            const int kc = kk * 32 + lg * 8;
            bf16x8 afrag[4], bfrag[4];
#pragma unroll
            for (int mi = 0; mi < 4; ++mi)
                afrag[mi] = *(const bf16x8*)&As[(wm * 64 + mi * 16 + lr) * BK + kc];
#pragma unroll
            for (int ni = 0; ni < 4; ++ni)
                bfrag[ni] = *(const bf16x8*)&Bs[(wn * 64 + ni * 16 + lr) * BK + kc];
#pragma unroll
            for (int mi = 0; mi < 4; ++mi)
#pragma unroll
                for (int ni = 0; ni < 4; ++ni)
                    acc[mi][ni] = __builtin_amdgcn_mfma_f32_16x16x32_bf16(
                        afrag[mi], bfrag[ni], acc[mi][ni], 0, 0, 0);
        }
        __syncthreads();
    }

    // --- epilogue: C/D layout col=lane&15, row=(lane>>4)*4+j  (m89/m91-verified)
    float* Cp = C + (size_t)(bm * BM + wm * 64) * OUT_F + (size_t)bn * BN + wn * 64;
#pragma unroll
    for (int mi = 0; mi < 4; ++mi)
#pragma unroll
        for (int ni = 0; ni < 4; ++ni)
#pragma unroll
            for (int j = 0; j < 4; ++j) {
                const int r = mi * 16 + lg * 4 + j;
                const int c = ni * 16 + lr;
                Cp[(size_t)r * OUT_F + c] = acc[mi][ni][j];
            }
}

extern "C" void kernel_launch(void* const* d_in, const int* in_sizes, int n_in,
                              void* d_out, int out_size, void* d_ws, size_t ws_size,
                              hipStream_t stream) {
    const float* x      = (const float*)d_in[0];
    const int*   tern   = (const int*)d_in[1];
    const float* scales = (const float*)d_in[2];
    // ste_gain / ste_temp (d_in[3], d_in[4]) affect only backward — unused.

    unsigned short* xb = (unsigned short*)d_ws;                   // 8192*4096 bf16 = 67.1 MB
    unsigned short* wb = xb + (size_t)TOKENS * IN_F;              // 4096*4096 bf16 = 33.6 MB

    cvt_x_kernel<<<TOKENS * IN_F / 8 / 256, 256, 0, stream>>>(x, xb);
    deq_w_kernel<<<OUT_F * IN_F / 8 / 256, 256, 0, stream>>>(tern, scales, wb);

    dim3 grid(OUT_F / BN, TOKENS / BM);
    gemm_bt_kernel<<<grid, 256, 0, stream>>>(xb, wb, (float*)d_out);
}

// Round 2
// 287.840 us; speedup vs baseline: 1.4216x; 1.4216x over previous
//
#include <hip/hip_runtime.h>

#define TOKENS 8192
#define IN_F   4096
#define OUT_F  4096

#define BM 256
#define BN 256
#define BK 64
#define NT (IN_F / BK)   // 64 K-tiles

typedef __attribute__((ext_vector_type(4))) float  f32x4;
typedef __attribute__((ext_vector_type(4))) int    i32x4;
typedef __attribute__((ext_vector_type(8))) unsigned short u16x8;
typedef __attribute__((ext_vector_type(8))) __bf16 bf16x8;

typedef const __attribute__((address_space(1))) void gas_void;
typedef __attribute__((address_space(3))) void las_void;

__device__ __forceinline__ unsigned short f2bf(float f) {
    unsigned int u = __builtin_bit_cast(unsigned int, f);
    u += 0x7fffu + ((u >> 16) & 1u);   // round-to-nearest-even
    return (unsigned short)(u >> 16);
}

__global__ __launch_bounds__(256) void cvt_x_kernel(const float* __restrict__ x,
                                                    unsigned short* __restrict__ xb) {
    const int t = blockIdx.x * 256 + threadIdx.x;
    const f32x4* p = (const f32x4*)x + (size_t)t * 2;
    f32x4 a = p[0], b = p[1];
    u16x8 o;
#pragma unroll
    for (int j = 0; j < 4; ++j) { o[j] = f2bf(a[j]); o[4 + j] = f2bf(b[j]); }
    ((u16x8*)xb)[t] = o;
}

__global__ __launch_bounds__(256) void deq_w_kernel(const int* __restrict__ tern,
                                                    const float* __restrict__ scales,
                                                    unsigned short* __restrict__ wb) {
    const int t = blockIdx.x * 256 + threadIdx.x;
    const float s = scales[t >> 4];
    const i32x4* p = (const i32x4*)tern + (size_t)t * 2;
    i32x4 a = p[0], b = p[1];
    u16x8 o;
#pragma unroll
    for (int j = 0; j < 4; ++j) {
        o[j]     = f2bf((float)a[j] * s);
        o[4 + j] = f2bf((float)b[j] * s);
    }
    ((u16x8*)wb)[t] = o;
}

// ---------------------------------------------------------------------------
// C[M][N] = A[M][K] * B[N][K]^T, bf16 in / fp32 out.
// 256x256 tile, BK=64, 8 waves (2M x 4N), per-wave output 128x64.
// 8-phase-style schedule: per K-tile 4 phases, counted vmcnt, T2 swizzle, T5.
// LDS: As[2][256][64] + Bs[2][256][64] bf16 = 128 KiB (double-buffered).
// Swizzle (involution): element (r,k) stored at column k ^ ((r&7)<<3).
// Half-tiles: H0=A rows 0-127, H1=A rows 128-255, H2=B rows 0-127, H3=B 128-255.
// Issue schedule (tile t, buf c=t&1):  P1: t+1.H2 -> c^1 | P2: t+1.H3 -> c^1 |
//   P3: t+2.H0 -> c (safe: all buf-c ds_reads done by end of P2) | P4: t+2.H1 -> c,
//   then vmcnt(4) (drains all of t+1, leaves t+2.H0/H1 = 4 loads in flight).
// ---------------------------------------------------------------------------

#define QUAD(MI0, NI0)                                                         \
  do {                                                                         \
    _Pragma("unroll") for (int mi = 0; mi < 4; ++mi)                           \
      _Pragma("unroll") for (int ni = 0; ni < 2; ++ni)                         \
        _Pragma("unroll") for (int kk = 0; kk < 2; ++kk)                       \
          acc[(MI0)+mi][(NI0)+ni] = __builtin_amdgcn_mfma_f32_16x16x32_bf16(   \
              a[(MI0)+mi][kk], b[(NI0)+ni][kk], acc[(MI0)+mi][(NI0)+ni],0,0,0);\
  } while (0)

__global__ __launch_bounds__(512, 2) void gemm_bt_kernel(
        const unsigned short* __restrict__ A,
        const unsigned short* __restrict__ B,
        float* __restrict__ C) {
    __shared__ __align__(16) unsigned short As[2 * 256 * 64];
    __shared__ __align__(16) unsigned short Bs[2 * 256 * 64];

    const int tid  = threadIdx.x;
    const int wave = tid >> 6;
    const int lane = tid & 63;
    const int wm   = wave >> 2;        // 0-1
    const int wn   = wave & 3;         // 0-3
    const int lg   = lane >> 4;        // 0-3
    const int lr   = lane & 15;        // 0-15

    // XCD-aware swizzle (512 blocks, 512%8==0 -> simple form is bijective)
    int bid = blockIdx.x;
    bid = (bid & 7) * (512 >> 3) + (bid >> 3);
    const int bm = bid >> 4;           // 0-31
    const int bn = bid & 15;           // 0-15

    const size_t a_row0 = (size_t)bm * BM;
    const size_t b_row0 = (size_t)bn * BN;

    // stage one half-tile (128 rows x 64 cols bf16 = 16 KiB): 2 loads/thread.
    // LDS dest linear; global source pre-swizzled (rule #21 both-sides).
    auto stage_half = [&](int buf, int half, int which, int k0) {
        const unsigned short* G = which ? B : A;
        const size_t grow0 = (which ? b_row0 : a_row0) + (size_t)half * 128;
        unsigned short* T = (which ? Bs : As) + buf * 16384 + half * 8192;
#pragma unroll
        for (int i = 0; i < 2; ++i) {
            const int qe    = (i * 512 + tid) * 8;          // elem offset in half
            const int row_h = qe >> 6;                      // 0..127
            const int cswz  = (qe & 63) ^ ((row_h & 7) << 3);
            const unsigned short* src = G + (grow0 + row_h) * IN_F + k0 + cswz;
            unsigned short* dst = T + (i * 512 + (wave << 6)) * 8; // wave-uniform
            __builtin_amdgcn_global_load_lds((gas_void*)src, (las_void*)dst, 16, 0, 0);
        }
    };

    f32x4  acc[8][4] = {};
    bf16x8 a[8][2], b[4][2];

    const int sw   = (lr & 7) << 3;
    const int ksw0 = (lg * 8) ^ sw;
    const int ksw1 = (32 + lg * 8) ^ sw;
    const int arow = (wm * 128 + lr) * 64;
    const int brow = (wn * 64  + lr) * 64;

    // ---- prologue: tile0 fully + tile1 A-halves; drain tile0, keep 4 in flight
    stage_half(0, 0, 0, 0);  stage_half(0, 1, 0, 0);
    stage_half(0, 0, 1, 0);  stage_half(0, 1, 1, 0);
    stage_half(1, 0, 0, BK); stage_half(1, 1, 0, BK);
    asm volatile("s_waitcnt vmcnt(4)" ::: "memory");
    __builtin_amdgcn_sched_barrier(0);
    __builtin_amdgcn_s_barrier();

    for (int t = 0; t < NT; ++t) {
        const int buf  = t & 1;
        const int base = buf * 16384;
        const int bufn = buf ^ 1;

        // ---- P1: read A mi0-3 + B ni0-1 (12 ds_read_b128); stage t+1.H2
#pragma unroll
        for (int mi = 0; mi < 4; ++mi) {
            a[mi][0] = *(const bf16x8*)&As[base + arow + mi * 1024 + ksw0];
            a[mi][1] = *(const bf16x8*)&As[base + arow + mi * 1024 + ksw1];
        }
#pragma unroll
        for (int ni = 0; ni < 2; ++ni) {
            b[ni][0] = *(const bf16x8*)&Bs[base + brow + ni * 1024 + ksw0];
            b[ni][1] = *(const bf16x8*)&Bs[base + brow + ni * 1024 + ksw1];
        }
        if (t + 1 < NT) stage_half(bufn, 0, 1, (t + 1) * BK);
        __builtin_amdgcn_s_barrier();
        asm volatile("s_waitcnt lgkmcnt(0)" ::: "memory");
        __builtin_amdgcn_sched_barrier(0);
        __builtin_amdgcn_s_setprio(1);
        QUAD(0, 0);
        __builtin_amdgcn_s_setprio(0);
        __builtin_amdgcn_s_barrier();

        // ---- P2: read A mi4-7 + B ni2-3; stage t+1.H3
#pragma unroll
        for (int mi = 4; mi < 8; ++mi) {
            a[mi][0] = *(const bf16x8*)&As[base + arow + mi * 1024 + ksw0];
            a[mi][1] = *(const bf16x8*)&As[base + arow + mi * 1024 + ksw1];
        }
#pragma unroll
        for (int ni = 2; ni < 4; ++ni) {
            b[ni][0] = *(const bf16x8*)&Bs[base + brow + ni * 1024 + ksw0];
            b[ni][1] = *(const bf16x8*)&Bs[base + brow + ni * 1024 + ksw1];
        }
        if (t + 1 < NT) stage_half(bufn, 1, 1, (t + 1) * BK);
        __builtin_amdgcn_s_barrier();
        asm volatile("s_waitcnt lgkmcnt(0)" ::: "memory");
        __builtin_amdgcn_sched_barrier(0);
        __builtin_amdgcn_s_setprio(1);
        QUAD(4, 2);
        __builtin_amdgcn_s_setprio(0);
        __builtin_amdgcn_s_barrier();

        // ---- P3: no ds_read (frags in regs); stage t+2.H0 into freed buf
        if (t + 2 < NT) stage_half(buf, 0, 0, (t + 2) * BK);
        __builtin_amdgcn_s_barrier();
        __builtin_amdgcn_s_setprio(1);
        QUAD(0, 2);
        __builtin_amdgcn_s_setprio(0);
        __builtin_amdgcn_s_barrier();

        // ---- P4: stage t+2.H1; counted vmcnt (never 0 mid-loop)
        if (t + 2 < NT) {
            stage_half(buf, 1, 0, (t + 2) * BK);
            asm volatile("s_waitcnt vmcnt(4)" ::: "memory");
        } else if (t + 1 < NT) {
            asm volatile("s_waitcnt vmcnt(0)" ::: "memory");
        }
        __builtin_amdgcn_sched_barrier(0);
        __builtin_amdgcn_s_barrier();
        __builtin_amdgcn_s_setprio(1);
        QUAD(4, 0);
        __builtin_amdgcn_s_setprio(0);
        __builtin_amdgcn_s_barrier();
    }

    // ---- epilogue: C/D layout col=lane&15, row=(lane>>4)*4+j
    float* Cp = C + (a_row0 + wm * 128) * (size_t)OUT_F + b_row0 + wn * 64;
#pragma unroll
    for (int mi = 0; mi < 8; ++mi)
#pragma unroll
        for (int ni = 0; ni < 4; ++ni)
#pragma unroll
            for (int j = 0; j < 4; ++j)
                Cp[(size_t)(mi * 16 + lg * 4 + j) * OUT_F + ni * 16 + lr] = acc[mi][ni][j];
}

extern "C" void kernel_launch(void* const* d_in, const int* in_sizes, int n_in,
                              void* d_out, int out_size, void* d_ws, size_t ws_size,
                              hipStream_t stream) {
    const float* x      = (const float*)d_in[0];
    const int*   tern   = (const int*)d_in[1];
    const float* scales = (const float*)d_in[2];

    unsigned short* xb = (unsigned short*)d_ws;
    unsigned short* wb = xb + (size_t)TOKENS * IN_F;

    cvt_x_kernel<<<TOKENS * IN_F / 8 / 256, 256, 0, stream>>>(x, xb);
    deq_w_kernel<<<OUT_F * IN_F / 8 / 256, 256, 0, stream>>>(tern, scales, wb);

    dim3 grid((TOKENS / BM) * (OUT_F / BN));   // 32*16 = 512
    gemm_bt_kernel<<<grid, 512, 0, stream>>>(xb, wb, (float*)d_out);
}